// Round 2
// baseline (358.364 us; speedup 1.0000x reference)
//
#include <hip/hip_runtime.h>

#define B_  2
#define L_  4096
#define DM_ 1024
#define H_  16
#define D_  64
#define M_  (B_ * L_)   // 8192

typedef unsigned short u16;
typedef short bf16x8 __attribute__((ext_vector_type(8)));   // 8 bf16 (4 VGPRs)
typedef float f32x4  __attribute__((ext_vector_type(4)));   // MFMA accumulator

typedef const __attribute__((address_space(1))) void* as1_cvp;
typedef __attribute__((address_space(3))) void* as3_vp;

__device__ __forceinline__ float b2f(u16 u) {
    union { unsigned int i; float f; } x; x.i = ((unsigned int)u) << 16; return x.f;
}
__device__ __forceinline__ u16 f2b(float f) {   // RNE bf16
    unsigned int x = __float_as_uint(f);
    return (u16)((x + 0x7fffu + ((x >> 16) & 1u)) >> 16);
}

// ---------------------------------------------------------------------------
// fp32 -> bf16 flat cast (float4 in, ushort4 out)
// ---------------------------------------------------------------------------
__global__ void cast_bf16_kernel(const float* __restrict__ in, u16* __restrict__ out, int n4) {
    int i = blockIdx.x * blockDim.x + threadIdx.x;
    if (i < n4) {
        float4 v = ((const float4*)in)[i];
        ushort4 o;
        o.x = f2b(v.x); o.y = f2b(v.y); o.z = f2b(v.z); o.w = f2b(v.w);
        ((ushort4*)out)[i] = o;
    }
}

// ---------------------------------------------------------------------------
// W (K x N fp32, row-major) -> Wt (N x K bf16, k-contiguous)
// ---------------------------------------------------------------------------
__global__ void transpose_cast_kernel(const float* __restrict__ W, u16* __restrict__ Wt) {
    __shared__ float tile[32][33];
    int tx = threadIdx.x;           // 0..31
    int ty = threadIdx.y;           // 0..7
    int n = blockIdx.x * 32 + tx;   // column of W
    int k0 = blockIdx.y * 32;       // row base of W
#pragma unroll
    for (int i = 0; i < 4; ++i)
        tile[ty + i * 8][tx] = W[(size_t)(k0 + ty + i * 8) * DM_ + n];
    __syncthreads();
#pragma unroll
    for (int i = 0; i < 4; ++i) {
        int nn = blockIdx.x * 32 + ty + i * 8;
        Wt[(size_t)nn * DM_ + k0 + tx] = f2b(tile[tx][ty + i * 8]);
    }
}

__global__ void zero_f32_kernel(float* __restrict__ p, int n) {
    int i = blockIdx.x * blockDim.x + threadIdx.x;
    if (i < n) p[i] = 0.f;
}

// ---------------------------------------------------------------------------
// C(MxN) = A(MxK) @ Bt(NxK)^T + bias, optional ELU+1, bf16 or fp32 out.
// m97-style: 128x128 tile, BK=64, global_load_lds width 16, 16x16x32 bf16 MFMA.
// ---------------------------------------------------------------------------
template <bool OUT_BF16, bool ELU>
__global__ __launch_bounds__(256, 3) void gemm_bt_kernel(
    const u16* __restrict__ A, const u16* __restrict__ Bt,
    const float* __restrict__ bias, void* __restrict__ Cout,
    int M, int N, int K)
{
    __shared__ __align__(16) u16 As[128 * 64];
    __shared__ __align__(16) u16 Bs[128 * 64];

    const int t    = threadIdx.x;
    const int lane = t & 63;
    const int wave = t >> 6;
    const int wr   = wave >> 1;     // 0..1 : wave row in 2x2 wave grid
    const int wc   = wave & 1;      // 0..1
    const int quad = lane >> 4;     // 0..3
    const int l16  = lane & 15;
    const int m0   = blockIdx.x * 128;
    const int n0   = blockIdx.y * 128;

    f32x4 acc[4][4] = {};

    for (int kt = 0; kt < K; kt += 64) {
#pragma unroll
        for (int i = 0; i < 4; ++i) {
            int c   = i * 256 + t;          // chunk id 0..1023
            int row = c >> 3;               // 0..127
            int kc  = c & 7;                // 0..7
            int cbase = i * 256 + wave * 64;   // wave-uniform chunk base
            const u16* gA = A  + (size_t)(m0 + row) * K + kt + kc * 8;
            const u16* gB = Bt + (size_t)(n0 + row) * K + kt + kc * 8;
            __builtin_amdgcn_global_load_lds((as1_cvp)gA, (as3_vp)(As + cbase * 8), 16, 0, 0);
            __builtin_amdgcn_global_load_lds((as1_cvp)gB, (as3_vp)(Bs + cbase * 8), 16, 0, 0);
        }
        __syncthreads();
#pragma unroll
        for (int ks = 0; ks < 2; ++ks) {
            bf16x8 af[4], bfr[4];
#pragma unroll
            for (int it = 0; it < 4; ++it)
                af[it] = *(const bf16x8*)(As + (wr * 64 + it * 16 + l16) * 64 + ks * 32 + quad * 8);
#pragma unroll
            for (int jt = 0; jt < 4; ++jt)
                bfr[jt] = *(const bf16x8*)(Bs + (wc * 64 + jt * 16 + l16) * 64 + ks * 32 + quad * 8);
#pragma unroll
            for (int it = 0; it < 4; ++it)
#pragma unroll
                for (int jt = 0; jt < 4; ++jt)
                    acc[it][jt] = __builtin_amdgcn_mfma_f32_16x16x32_bf16(
                        af[it], bfr[jt], acc[it][jt], 0, 0, 0);
        }
        __syncthreads();
    }

    // epilogue: C/D layout col=lane&15, row=quad*4+reg (m89/m91 verified)
#pragma unroll
    for (int it = 0; it < 4; ++it) {
        int row0 = m0 + wr * 64 + it * 16 + quad * 4;
#pragma unroll
        for (int jt = 0; jt < 4; ++jt) {
            int col = n0 + wc * 64 + jt * 16 + l16;
            float bv = bias[col];
#pragma unroll
            for (int r = 0; r < 4; ++r) {
                float x = acc[it][jt][r] + bv;
                if (ELU) x = (x > 0.f) ? (x + 1.f) : __expf(x);
                if (OUT_BF16)
                    ((u16*)Cout)[(size_t)(row0 + r) * N + col] = f2b(x);
                else
                    ((float*)Cout)[(size_t)(row0 + r) * N + col] = x;
            }
        }
    }
}

// ---------------------------------------------------------------------------
// S[bh][e][d] += sum_l K[l,e]*Q[l,d]  (atomic partials over L-chunks of 256)
// denom[bh][l] = q[l]·k[l] + 1e-6
// ---------------------------------------------------------------------------
__global__ __launch_bounds__(256) void attn_s_kernel(
    const u16* __restrict__ Qp, const u16* __restrict__ Kp,
    float* __restrict__ S, float* __restrict__ denom)
{
    __shared__ __align__(16) float Qs[64][68];
    __shared__ __align__(16) float Ks[64][68];
    const int t  = threadIdx.x;
    const int bh = blockIdx.x;            // b*H + h
    const int b  = bh >> 4, h = bh & 15;
    const int l0 = blockIdx.y * 256;
    const size_t base = (size_t)b * L_ * DM_ + h * 64;

    const int e0 = (t >> 4) * 4;
    const int d0 = (t & 15) * 4;
    float acc[4][4] = {};

    for (int sub = 0; sub < 4; ++sub) {
        int lb = l0 + sub * 64;
        {   // stage 64 rows x 64 cols: 256 threads x 8 elems x 2 row-halves
            int row = t >> 3;            // 0..31
            int c8  = (t & 7) * 8;       // 0..56
#pragma unroll
            for (int r2 = 0; r2 < 2; ++r2) {
                int rr = row + r2 * 32;
                const u16* gq = Qp + base + (size_t)(lb + rr) * DM_ + c8;
                const u16* gk = Kp + base + (size_t)(lb + rr) * DM_ + c8;
                uint4 q8 = *(const uint4*)gq;
                uint4 k8 = *(const uint4*)gk;
                const u16* q16 = (const u16*)&q8;
                const u16* k16 = (const u16*)&k8;
#pragma unroll
                for (int u = 0; u < 8; ++u) {
                    Qs[rr][c8 + u] = b2f(q16[u]);
                    Ks[rr][c8 + u] = b2f(k16[u]);
                }
            }
        }
        __syncthreads();
        {   // denom: 4 threads per row, 16 dims each, shfl reduce
            int dl = t >> 2, p = t & 3;
            float s = 0.f;
#pragma unroll
            for (int u = 0; u < 16; ++u) s += Qs[dl][p * 16 + u] * Ks[dl][p * 16 + u];
            s += __shfl_xor(s, 1);
            s += __shfl_xor(s, 2);
            if (p == 0) denom[(size_t)bh * L_ + lb + dl] = s + 1e-6f;
        }
#pragma unroll 8
        for (int l = 0; l < 64; ++l) {
            float4 kv = *(const float4*)&Ks[l][e0];
            float4 qv = *(const float4*)&Qs[l][d0];
            const float* kk = (const float*)&kv;
            const float* qq = (const float*)&qv;
#pragma unroll
            for (int i = 0; i < 4; ++i)
#pragma unroll
                for (int j = 0; j < 4; ++j)
                    acc[i][j] += kk[i] * qq[j];
        }
        __syncthreads();
    }
    float* Sbh = S + (size_t)bh * 4096;
#pragma unroll
    for (int i = 0; i < 4; ++i)
#pragma unroll
        for (int j = 0; j < 4; ++j)
            atomicAdd(&Sbh[(e0 + i) * 64 + d0 + j], acc[i][j]);
}

// ---------------------------------------------------------------------------
// ctx[b][l][h*64+d] = (sum_e V[l,e]*S[e,d]) / denom[l]   (bf16 out)
// ---------------------------------------------------------------------------
__global__ __launch_bounds__(256) void attn_out_kernel(
    const u16* __restrict__ Vp, const float* __restrict__ S,
    const float* __restrict__ denom, u16* __restrict__ ctx)
{
    __shared__ __align__(16) float Vs[64][68];
    __shared__ __align__(16) float St[64][68];   // St[d][e] = S[e][d]
    const int t  = threadIdx.x;
    const int bh = blockIdx.x;
    const int b  = bh >> 4, h = bh & 15;
    const int lb = blockIdx.y * 64;
    const size_t base = (size_t)b * L_ * DM_ + h * 64;

    {   // stage 64 rows x 64 cols: 256 threads x 8 elems x 2 row-halves
        int row = t >> 3;            // 0..31
        int c8  = (t & 7) * 8;       // 0..56
#pragma unroll
        for (int r2 = 0; r2 < 2; ++r2) {
            int rr = row + r2 * 32;
            const u16* gv = Vp + base + (size_t)(lb + rr) * DM_ + c8;
            uint4 v8 = *(const uint4*)gv;
            const u16* v16 = (const u16*)&v8;
#pragma unroll
            for (int u = 0; u < 8; ++u) Vs[rr][c8 + u] = b2f(v16[u]);
        }
    }
    {
        const float* Sbh = S + (size_t)bh * 4096;
        for (int idx = t; idx < 4096; idx += 256) {
            int e = idx >> 6, d = idx & 63;
            St[d][e] = Sbh[idx];
        }
    }
    __syncthreads();

    const int l0 = (t >> 4) * 4;
    const int d0 = (t & 15) * 4;
    float acc[4][4] = {};
#pragma unroll 4
    for (int e4 = 0; e4 < 16; ++e4) {
        float4 vv[4], sv[4];
#pragma unroll
        for (int i = 0; i < 4; ++i) vv[i] = *(const float4*)&Vs[l0 + i][e4 * 4];
#pragma unroll
        for (int j = 0; j < 4; ++j) sv[j] = *(const float4*)&St[d0 + j][e4 * 4];
#pragma unroll
        for (int i = 0; i < 4; ++i) {
            const float* a = (const float*)&vv[i];
#pragma unroll
            for (int j = 0; j < 4; ++j) {
                const float* s = (const float*)&sv[j];
                acc[i][j] += a[0] * s[0] + a[1] * s[1] + a[2] * s[2] + a[3] * s[3];
            }
        }
    }
#pragma unroll
    for (int i = 0; i < 4; ++i) {
        float inv = 1.f / denom[(size_t)bh * L_ + lb + l0 + i];
#pragma unroll
        for (int j = 0; j < 4; ++j)
            ctx[base + (size_t)(lb + l0 + i) * DM_ + d0 + j] = f2b(acc[i][j] * inv);
    }
}

// ---------------------------------------------------------------------------
extern "C" void kernel_launch(void* const* d_in, const int* in_sizes, int n_in,
                              void* d_out, int out_size, void* d_ws, size_t ws_size,
                              hipStream_t stream)
{
    const float* query = (const float*)d_in[0];
    const float* key   = (const float*)d_in[1];
    const float* value = (const float*)d_in[2];
    const float* Wq = (const float*)d_in[3];  const float* bq = (const float*)d_in[4];
    const float* Wk = (const float*)d_in[5];  const float* bk = (const float*)d_in[6];
    const float* Wv = (const float*)d_in[7];  const float* bv = (const float*)d_in[8];
    const float* Wo = (const float*)d_in[9];  const float* bo = (const float*)d_in[10];

    const size_t SZ = (size_t)M_ * DM_ * sizeof(u16);   // 16.78 MB per bf16 tensor
    char* ws = (char*)d_ws;
    u16* qb  = (u16*)(ws + 0 * SZ);
    u16* kb  = (u16*)(ws + 1 * SZ);
    u16* vb  = (u16*)(ws + 2 * SZ);
    u16* Qp  = (u16*)(ws + 3 * SZ);
    u16* Kp  = (u16*)(ws + 4 * SZ);
    u16* Vp  = qb;    // qb dead after Q projection
    u16* ctx = kb;    // kb dead after K projection
    u16* Wqt = (u16*)(ws + 5 * SZ);
    u16* Wkt = Wqt + (size_t)DM_ * DM_;
    u16* Wvt = Wkt + (size_t)DM_ * DM_;
    u16* Wot = Wvt + (size_t)DM_ * DM_;
    float* S     = (float*)(ws + 5 * SZ + 4 * (size_t)DM_ * DM_ * sizeof(u16));
    float* denom = S + (size_t)B_ * H_ * D_ * D_;

    // 1. weights: transpose + cast to bf16 (N x K)
    dim3 tb(32, 8), tg(32, 32);
    transpose_cast_kernel<<<tg, tb, 0, stream>>>(Wq, Wqt);
    transpose_cast_kernel<<<tg, tb, 0, stream>>>(Wk, Wkt);
    transpose_cast_kernel<<<tg, tb, 0, stream>>>(Wv, Wvt);
    transpose_cast_kernel<<<tg, tb, 0, stream>>>(Wo, Wot);

    // 2. activations: cast to bf16
    int n4 = M_ * DM_ / 4;
    cast_bf16_kernel<<<n4 / 256, 256, 0, stream>>>(query, qb, n4);
    cast_bf16_kernel<<<n4 / 256, 256, 0, stream>>>(key,   kb, n4);
    cast_bf16_kernel<<<n4 / 256, 256, 0, stream>>>(value, vb, n4);

    // 3. zero S accumulator
    int nS = B_ * H_ * D_ * D_;
    zero_f32_kernel<<<nS / 256, 256, 0, stream>>>(S, nS);

    // 4. projections (fused bias + ELU+1 for q,k)
    dim3 gg(M_ / 128, DM_ / 128);
    gemm_bt_kernel<true, true ><<<gg, 256, 0, stream>>>(qb, Wqt, bq, Qp, M_, DM_, DM_);
    gemm_bt_kernel<true, true ><<<gg, 256, 0, stream>>>(kb, Wkt, bk, Kp, M_, DM_, DM_);
    gemm_bt_kernel<true, false><<<gg, 256, 0, stream>>>(vb, Wvt, bv, Vp, M_, DM_, DM_);

    // 5. S = K^T Q per head (+denom)
    attn_s_kernel<<<dim3(B_ * H_, L_ / 256), 256, 0, stream>>>(Qp, Kp, S, denom);

    // 6. out = V S / denom -> ctx (bf16, combined-head layout)
    attn_out_kernel<<<dim3(B_ * H_, L_ / 64), 256, 0, stream>>>(Vp, S, denom, ctx);

    // 7. final projection -> fp32 d_out
    gemm_bt_kernel<false, false><<<gg, 256, 0, stream>>>(ctx, Wot, bo, (float*)d_out, M_, DM_, DM_);
}

// Round 3
// 321.323 us; speedup vs baseline: 1.1153x; 1.1153x over previous
//
#include <hip/hip_runtime.h>

#define B_  2
#define L_  4096
#define DM_ 1024
#define H_  16
#define D_  64
#define M_  (B_ * L_)   // 8192

typedef unsigned short u16;
typedef short bf16x8 __attribute__((ext_vector_type(8)));   // 8 bf16 (4 VGPRs)
typedef float f32x4  __attribute__((ext_vector_type(4)));   // MFMA accumulator

typedef const __attribute__((address_space(1))) void* as1_cvp;
typedef __attribute__((address_space(3))) void* as3_vp;

__device__ __forceinline__ float b2f(u16 u) {
    union { unsigned int i; float f; } x; x.i = ((unsigned int)u) << 16; return x.f;
}
__device__ __forceinline__ u16 f2b(float f) {   // RNE bf16
    unsigned int x = __float_as_uint(f);
    return (u16)((x + 0x7fffu + ((x >> 16) & 1u)) >> 16);
}

// ---------------------------------------------------------------------------
// fp32 -> bf16 flat cast
// ---------------------------------------------------------------------------
__global__ void cast_bf16_kernel(const float* __restrict__ in, u16* __restrict__ out, int n4) {
    int i = blockIdx.x * blockDim.x + threadIdx.x;
    if (i < n4) {
        float4 v = ((const float4*)in)[i];
        ushort4 o;
        o.x = f2b(v.x); o.y = f2b(v.y); o.z = f2b(v.z); o.w = f2b(v.w);
        ((ushort4*)out)[i] = o;
    }
}

// ---------------------------------------------------------------------------
// W (K x N fp32, row-major) -> Wt (N x K bf16, k-contiguous)
// ---------------------------------------------------------------------------
__global__ void transpose_cast_kernel(const float* __restrict__ W, u16* __restrict__ Wt) {
    __shared__ float tile[32][33];
    int tx = threadIdx.x, ty = threadIdx.y;
    int n = blockIdx.x * 32 + tx;
    int k0 = blockIdx.y * 32;
#pragma unroll
    for (int i = 0; i < 4; ++i)
        tile[ty + i * 8][tx] = W[(size_t)(k0 + ty + i * 8) * DM_ + n];
    __syncthreads();
#pragma unroll
    for (int i = 0; i < 4; ++i) {
        int nn = blockIdx.x * 32 + ty + i * 8;
        Wt[(size_t)nn * DM_ + k0 + tx] = f2b(tile[tx][ty + i * 8]);
    }
}

__global__ void zero_f32_kernel(float* __restrict__ p, int n) {
    int i = blockIdx.x * blockDim.x + threadIdx.x;
    if (i < n) p[i] = 0.f;
}

// ---------------------------------------------------------------------------
// C(MxN) = A(MxK) @ Bt(NxK)^T + bias.
// MODE 0: fp32 natural out.  MODE 1: bf16 natural out.
// MODE 2: bf16 per-head TRANSPOSED out: Cout[bh][e][l] (l-contiguous),
//         bh = (row/4096)*16 + col/64, e = col%64, l = row%4096.
//         Done via LDS transpose of the 128x128 C tile.
// ---------------------------------------------------------------------------
template <int MODE, bool ELU>
__global__ __launch_bounds__(256, 3) void gemm_bt_kernel(
    const u16* __restrict__ A, const u16* __restrict__ Bt,
    const float* __restrict__ bias, void* __restrict__ Cout,
    int M, int N, int K)
{
    __shared__ __align__(16) u16 smem[MODE == 2 ? 17408 : 16384];
    u16* As = smem;
    u16* Bs = smem + 8192;

    const int t    = threadIdx.x;
    const int lane = t & 63;
    const int wave = t >> 6;
    const int wr   = wave >> 1;
    const int wc   = wave & 1;
    const int quad = lane >> 4;
    const int l16  = lane & 15;
    const int m0   = blockIdx.x * 128;
    const int n0   = blockIdx.y * 128;

    f32x4 acc[4][4] = {};

    for (int kt = 0; kt < K; kt += 64) {
#pragma unroll
        for (int i = 0; i < 4; ++i) {
            int c   = i * 256 + t;          // chunk id 0..1023
            int row = c >> 3;               // 0..127
            int kc  = c & 7;                // 0..7
            int cbase = i * 256 + wave * 64;   // wave-uniform chunk base
            const u16* gA = A  + (size_t)(m0 + row) * K + kt + kc * 8;
            const u16* gB = Bt + (size_t)(n0 + row) * K + kt + kc * 8;
            __builtin_amdgcn_global_load_lds((as1_cvp)gA, (as3_vp)(As + cbase * 8), 16, 0, 0);
            __builtin_amdgcn_global_load_lds((as1_cvp)gB, (as3_vp)(Bs + cbase * 8), 16, 0, 0);
        }
        __syncthreads();
#pragma unroll
        for (int ks = 0; ks < 2; ++ks) {
            bf16x8 af[4], bfr[4];
#pragma unroll
            for (int it = 0; it < 4; ++it)
                af[it] = *(const bf16x8*)(As + (wr * 64 + it * 16 + l16) * 64 + ks * 32 + quad * 8);
#pragma unroll
            for (int jt = 0; jt < 4; ++jt)
                bfr[jt] = *(const bf16x8*)(Bs + (wc * 64 + jt * 16 + l16) * 64 + ks * 32 + quad * 8);
#pragma unroll
            for (int it = 0; it < 4; ++it)
#pragma unroll
                for (int jt = 0; jt < 4; ++jt)
                    acc[it][jt] = __builtin_amdgcn_mfma_f32_16x16x32_bf16(
                        af[it], bfr[jt], acc[it][jt], 0, 0, 0);
        }
        __syncthreads();
    }

    if (MODE != 2) {
        // C/D layout col=lane&15, row=quad*4+reg (m89/m91 verified)
#pragma unroll
        for (int it = 0; it < 4; ++it) {
            int row0 = m0 + wr * 64 + it * 16 + quad * 4;
#pragma unroll
            for (int jt = 0; jt < 4; ++jt) {
                int col = n0 + wc * 64 + jt * 16 + l16;
                float bv = bias[col];
#pragma unroll
                for (int r = 0; r < 4; ++r) {
                    float x = acc[it][jt][r] + bv;
                    if (ELU) x = (x > 0.f) ? (x + 1.f) : __expf(x);
                    if (MODE == 1)
                        ((u16*)Cout)[(size_t)(row0 + r) * N + col] = f2b(x);
                    else
                        ((float*)Cout)[(size_t)(row0 + r) * N + col] = x;
                }
            }
        }
    } else {
        // transpose C tile through LDS: Ct[col][row], stride 136 u16 (16B-aligned rows)
        u16* Ct = smem;
#pragma unroll
        for (int it = 0; it < 4; ++it) {
            int row0 = wr * 64 + it * 16 + quad * 4;     // block-rel row
#pragma unroll
            for (int jt = 0; jt < 4; ++jt) {
                int colr = wc * 64 + jt * 16 + l16;      // block-rel col
                float bv = bias[n0 + colr];
                ushort4 o;
                float x0 = acc[it][jt][0] + bv;
                float x1 = acc[it][jt][1] + bv;
                float x2 = acc[it][jt][2] + bv;
                float x3 = acc[it][jt][3] + bv;
                if (ELU) {
                    x0 = (x0 > 0.f) ? (x0 + 1.f) : __expf(x0);
                    x1 = (x1 > 0.f) ? (x1 + 1.f) : __expf(x1);
                    x2 = (x2 > 0.f) ? (x2 + 1.f) : __expf(x2);
                    x3 = (x3 > 0.f) ? (x3 + 1.f) : __expf(x3);
                }
                o.x = f2b(x0); o.y = f2b(x1); o.z = f2b(x2); o.w = f2b(x3);
                *(ushort4*)&Ct[colr * 136 + row0] = o;
            }
        }
        __syncthreads();
        // coalesced readout: 16 cols x 16 segs per pass, 8 passes
        int b   = m0 >> 12;          // batch (blocks never straddle: 4096%128==0)
        int seg = t & 15;
        int cg  = t >> 4;
#pragma unroll
        for (int iter = 0; iter < 8; ++iter) {
            int colIdx = iter * 16 + cg;
            int gcol = n0 + colIdx;
            int bh = b * 16 + (gcol >> 6);
            int e  = gcol & 63;
            uint4 v = *(const uint4*)&Ct[colIdx * 136 + seg * 8];
            *(uint4*)((u16*)Cout + ((size_t)bh << 18) + ((size_t)e << 12)
                      + (m0 & 4095) + seg * 8) = v;
        }
    }
}

// ---------------------------------------------------------------------------
// attn_s: S[bh][e][d] += sum_l KpT[bh][e][l] * QpT[bh][d][l]   (MFMA, k=l)
// + denom[bh][l] = sum_e QpT[e][l]*KpT[e][l] + 1e-6
// Inputs l-contiguous -> direct global->VGPR fragments, no LDS.
// ---------------------------------------------------------------------------
__global__ __launch_bounds__(256) void attn_s_kernel(
    const u16* __restrict__ QpT, const u16* __restrict__ KpT,
    float* __restrict__ S, float* __restrict__ denom)
{
    const int t    = threadIdx.x;
    const int lane = t & 63;
    const int wave = t >> 6;
    const int quad = lane >> 4;
    const int l16  = lane & 15;
    const int bh   = blockIdx.x;
    const int lc   = blockIdx.y * 256;

    const u16* baseQ = QpT + ((size_t)bh << 18);
    const u16* baseK = KpT + ((size_t)bh << 18);

    // MFMA: wave w owns e-rows [w*16, w*16+16), all 64 d (4 tiles)
    f32x4 acc[4] = {};
    const u16* arow = baseK + (size_t)(wave * 16 + l16) * 4096 + lc;
#pragma unroll
    for (int ks = 0; ks < 8; ++ks) {
        int koff = ks * 32 + quad * 8;
        bf16x8 a = *(const bf16x8*)(arow + koff);
#pragma unroll
        for (int dt = 0; dt < 4; ++dt) {
            bf16x8 b = *(const bf16x8*)(baseQ + (size_t)(dt * 16 + l16) * 4096 + lc + koff);
            acc[dt] = __builtin_amdgcn_mfma_f32_16x16x32_bf16(a, b, acc[dt], 0, 0, 0);
        }
    }
    float* Sb = S + (size_t)bh * 4096;
#pragma unroll
    for (int dt = 0; dt < 4; ++dt)
#pragma unroll
        for (int r = 0; r < 4; ++r)
            atomicAdd(&Sb[(wave * 16 + quad * 4 + r) * 64 + dt * 16 + l16], acc[dt][r]);

    // denom: threads 0..127 handle l = lc + 2t, 2t+1 (u32-pair loads)
    if (t < 128) {
        float s0 = 0.f, s1 = 0.f;
        int off = lc + 2 * t;
#pragma unroll 8
        for (int e = 0; e < 64; ++e) {
            unsigned int qv = *(const unsigned int*)(baseQ + (size_t)e * 4096 + off);
            unsigned int kv = *(const unsigned int*)(baseK + (size_t)e * 4096 + off);
            s0 += b2f((u16)(qv & 0xffff)) * b2f((u16)(kv & 0xffff));
            s1 += b2f((u16)(qv >> 16))   * b2f((u16)(kv >> 16));
        }
        denom[(size_t)bh * 4096 + off]     = s0 + 1e-6f;
        denom[(size_t)bh * 4096 + off + 1] = s1 + 1e-6f;
    }
}

// ---------------------------------------------------------------------------
// attn_out: ctx[b][l][h*64+d] = (sum_e V[l][e] * S[e][d]) / denom[l]  (MFMA)
// A = V natural layout (m=l, k=e contiguous); B = S^T staged bf16 in LDS.
// ---------------------------------------------------------------------------
__global__ __launch_bounds__(256) void attn_out_kernel(
    const u16* __restrict__ Vp, const float* __restrict__ S,
    const float* __restrict__ denom, u16* __restrict__ ctx)
{
    __shared__ __align__(16) u16 Sb[64 * 64];   // Sb[d][e], e contiguous
    __shared__ float dsh[256];
    const int t    = threadIdx.x;
    const int lane = t & 63;
    const int wave = t >> 6;
    const int quad = lane >> 4;
    const int l16  = lane & 15;
    const int bh   = blockIdx.x;
    const int b    = bh >> 4, h = bh & 15;
    const int lc   = blockIdx.y * 256;

    {   // stage S transposed to bf16: thread t reads S[e][d0..d0+15]
        const float* Sg = S + (size_t)bh * 4096;
        int e = t >> 2, d0 = (t & 3) * 16;
#pragma unroll
        for (int i = 0; i < 16; ++i)
            Sb[(d0 + i) * 64 + e] = f2b(Sg[e * 64 + d0 + i]);
        dsh[t] = denom[(size_t)bh * 4096 + lc + t];
    }
    __syncthreads();

    // wave w owns l-rows [w*64, w*64+64) (4 tiles), all 64 d (4 tiles)
    const u16* Abase = Vp + (size_t)b * L_ * DM_ + (size_t)(lc + wave * 64 + l16) * DM_ + h * 64;
    f32x4 acc[4][4] = {};
#pragma unroll
    for (int ks = 0; ks < 2; ++ks) {
        int koff = ks * 32 + quad * 8;
        bf16x8 af[4], bfr[4];
#pragma unroll
        for (int lt = 0; lt < 4; ++lt)
            af[lt] = *(const bf16x8*)(Abase + (size_t)(lt * 16) * DM_ + koff);
#pragma unroll
        for (int dt = 0; dt < 4; ++dt)
            bfr[dt] = *(const bf16x8*)(Sb + (dt * 16 + l16) * 64 + koff);
#pragma unroll
        for (int lt = 0; lt < 4; ++lt)
#pragma unroll
            for (int dt = 0; dt < 4; ++dt)
                acc[lt][dt] = __builtin_amdgcn_mfma_f32_16x16x32_bf16(
                    af[lt], bfr[dt], acc[lt][dt], 0, 0, 0);
    }

    u16* cbase = ctx + (size_t)b * L_ * DM_ + h * 64;
#pragma unroll
    for (int lt = 0; lt < 4; ++lt) {
        int lrow0 = wave * 64 + lt * 16 + quad * 4;
        float inv[4];
#pragma unroll
        for (int r = 0; r < 4; ++r) inv[r] = 1.f / dsh[lrow0 + r];
#pragma unroll
        for (int dt = 0; dt < 4; ++dt) {
            int d = dt * 16 + l16;
#pragma unroll
            for (int r = 0; r < 4; ++r)
                cbase[(size_t)(lc + lrow0 + r) * DM_ + d] = f2b(acc[lt][dt][r] * inv[r]);
        }
    }
}

// ---------------------------------------------------------------------------
extern "C" void kernel_launch(void* const* d_in, const int* in_sizes, int n_in,
                              void* d_out, int out_size, void* d_ws, size_t ws_size,
                              hipStream_t stream)
{
    const float* query = (const float*)d_in[0];
    const float* key   = (const float*)d_in[1];
    const float* value = (const float*)d_in[2];
    const float* Wq = (const float*)d_in[3];  const float* bq = (const float*)d_in[4];
    const float* Wk = (const float*)d_in[5];  const float* bk = (const float*)d_in[6];
    const float* Wv = (const float*)d_in[7];  const float* bv = (const float*)d_in[8];
    const float* Wo = (const float*)d_in[9];  const float* bo = (const float*)d_in[10];

    const size_t SZ = (size_t)M_ * DM_ * sizeof(u16);   // 16.78 MB per bf16 tensor
    char* ws = (char*)d_ws;
    u16* qb  = (u16*)(ws + 0 * SZ);
    u16* kb  = (u16*)(ws + 1 * SZ);
    u16* vb  = (u16*)(ws + 2 * SZ);
    u16* QpT = (u16*)(ws + 3 * SZ);   // [bh][e][l] l-contiguous
    u16* KpT = (u16*)(ws + 4 * SZ);
    u16* Vp  = qb;    // qb dead after Q projection
    u16* ctx = kb;    // kb dead after K projection
    u16* Wqt = (u16*)(ws + 5 * SZ);
    u16* Wkt = Wqt + (size_t)DM_ * DM_;
    u16* Wvt = Wkt + (size_t)DM_ * DM_;
    u16* Wot = Wvt + (size_t)DM_ * DM_;
    float* S     = (float*)(ws + 5 * SZ + 4 * (size_t)DM_ * DM_ * sizeof(u16));
    float* denom = S + (size_t)B_ * H_ * D_ * D_;

    // 1. weights: transpose + cast to bf16 (N x K)
    dim3 tb(32, 8), tg(32, 32);
    transpose_cast_kernel<<<tg, tb, 0, stream>>>(Wq, Wqt);
    transpose_cast_kernel<<<tg, tb, 0, stream>>>(Wk, Wkt);
    transpose_cast_kernel<<<tg, tb, 0, stream>>>(Wv, Wvt);
    transpose_cast_kernel<<<tg, tb, 0, stream>>>(Wo, Wot);

    // 2. activations: cast to bf16
    int n4 = M_ * DM_ / 4;
    cast_bf16_kernel<<<n4 / 256, 256, 0, stream>>>(query, qb, n4);
    cast_bf16_kernel<<<n4 / 256, 256, 0, stream>>>(key,   kb, n4);
    cast_bf16_kernel<<<n4 / 256, 256, 0, stream>>>(value, vb, n4);

    // 3. zero S accumulator
    int nS = B_ * H_ * D_ * D_;
    zero_f32_kernel<<<nS / 256, 256, 0, stream>>>(S, nS);

    // 4. projections: Q,K -> per-head transposed bf16 (+bias+ELU+1); V natural bf16
    dim3 gg(M_ / 128, DM_ / 128);
    gemm_bt_kernel<2, true ><<<gg, 256, 0, stream>>>(qb, Wqt, bq, QpT, M_, DM_, DM_);
    gemm_bt_kernel<2, true ><<<gg, 256, 0, stream>>>(kb, Wkt, bk, KpT, M_, DM_, DM_);
    gemm_bt_kernel<1, false><<<gg, 256, 0, stream>>>(vb, Wvt, bv, Vp, M_, DM_, DM_);

    // 5. S = K^T Q per head (+denom), MFMA over l
    attn_s_kernel<<<dim3(B_ * H_, L_ / 256), 256, 0, stream>>>(QpT, KpT, S, denom);

    // 6. out = V S / denom -> ctx (bf16, combined-head layout), MFMA
    attn_out_kernel<<<dim3(B_ * H_, L_ / 256), 256, 0, stream>>>(Vp, S, denom, ctx);

    // 7. final projection -> fp32 d_out
    gemm_bt_kernel<0, false><<<gg, 256, 0, stream>>>(ctx, Wot, bo, (float*)d_out, M_, DM_, DM_);
}

// Round 4
// 285.561 us; speedup vs baseline: 1.2549x; 1.1252x over previous
//
#include <hip/hip_runtime.h>

#define B_  2
#define L_  4096
#define DM_ 1024
#define H_  16
#define D_  64
#define M_  (B_ * L_)   // 8192

typedef unsigned short u16;
typedef short bf16x8 __attribute__((ext_vector_type(8)));   // 8 bf16 (4 VGPRs)
typedef float f32x4  __attribute__((ext_vector_type(4)));   // MFMA accumulator

typedef const __attribute__((address_space(1))) void* as1_cvp;
typedef __attribute__((address_space(3))) void* as3_vp;

__device__ __forceinline__ float b2f(u16 u) {
    union { unsigned int i; float f; } x; x.i = ((unsigned int)u) << 16; return x.f;
}
__device__ __forceinline__ u16 f2b(float f) {   // RNE bf16
    unsigned int x = __float_as_uint(f);
    return (u16)((x + 0x7fffu + ((x >> 16) & 1u)) >> 16);
}

// ---------------------------------------------------------------------------
// fp32 -> bf16 flat cast, batched over 3 tensors via blockIdx.z
// ---------------------------------------------------------------------------
__global__ void cast3_bf16_kernel(const float* __restrict__ i0, const float* __restrict__ i1,
                                  const float* __restrict__ i2,
                                  u16* __restrict__ o0, u16* __restrict__ o1, u16* __restrict__ o2,
                                  int n4) {
    int z = blockIdx.z;
    const float* in = z == 0 ? i0 : (z == 1 ? i1 : i2);
    u16* out       = z == 0 ? o0 : (z == 1 ? o1 : o2);
    int i = blockIdx.x * blockDim.x + threadIdx.x;
    if (i < n4) {
        float4 v = ((const float4*)in)[i];
        ushort4 o;
        o.x = f2b(v.x); o.y = f2b(v.y); o.z = f2b(v.z); o.w = f2b(v.w);
        ((ushort4*)out)[i] = o;
    }
}

// ---------------------------------------------------------------------------
// W (K x N fp32, row-major) -> Wt (N x K bf16, k-contiguous); 4 weights via z
// ---------------------------------------------------------------------------
__global__ void transpose4_cast_kernel(const float* __restrict__ w0, const float* __restrict__ w1,
                                       const float* __restrict__ w2, const float* __restrict__ w3,
                                       u16* __restrict__ t0, u16* __restrict__ t1,
                                       u16* __restrict__ t2, u16* __restrict__ t3) {
    int z = blockIdx.z;
    const float* W = z == 0 ? w0 : z == 1 ? w1 : z == 2 ? w2 : w3;
    u16* Wt        = z == 0 ? t0 : z == 1 ? t1 : z == 2 ? t2 : t3;
    __shared__ float tile[32][33];
    int tx = threadIdx.x, ty = threadIdx.y;
    int n = blockIdx.x * 32 + tx;
    int k0 = blockIdx.y * 32;
#pragma unroll
    for (int i = 0; i < 4; ++i)
        tile[ty + i * 8][tx] = W[(size_t)(k0 + ty + i * 8) * DM_ + n];
    __syncthreads();
#pragma unroll
    for (int i = 0; i < 4; ++i) {
        int nn = blockIdx.x * 32 + ty + i * 8;
        Wt[(size_t)nn * DM_ + k0 + tx] = f2b(tile[tx][ty + i * 8]);
    }
}

__global__ void zero_f32_kernel(float* __restrict__ p, int n) {
    int i = blockIdx.x * blockDim.x + threadIdx.x;
    if (i < n) p[i] = 0.f;
}

// ---------------------------------------------------------------------------
// QKV projections batched via blockIdx.z (z=0:Q, 1:K -> transposed+ELU out;
// z=2:V -> natural bf16 out). Same verified m97 K-loop as gemm_bt_kernel.
// ---------------------------------------------------------------------------
__global__ __launch_bounds__(256, 3) void gemm_qkv_kernel(
    const u16* __restrict__ qb, const u16* __restrict__ kb, const u16* __restrict__ vb,
    const u16* __restrict__ Wqt, const u16* __restrict__ Wkt, const u16* __restrict__ Wvt,
    const float* __restrict__ bq, const float* __restrict__ bk, const float* __restrict__ bv,
    u16* __restrict__ QpT, u16* __restrict__ KpT, u16* __restrict__ Vp)
{
    const int z = blockIdx.z;
    const u16* A    = z == 0 ? qb  : z == 1 ? kb  : vb;
    const u16* Bt   = z == 0 ? Wqt : z == 1 ? Wkt : Wvt;
    const float* bias = z == 0 ? bq : z == 1 ? bk : bv;

    __shared__ __align__(16) u16 smem[17408];
    u16* As = smem;
    u16* Bs = smem + 8192;

    const int t    = threadIdx.x;
    const int lane = t & 63;
    const int wave = t >> 6;
    const int wr   = wave >> 1;
    const int wc   = wave & 1;
    const int quad = lane >> 4;
    const int l16  = lane & 15;
    const int m0   = blockIdx.x * 128;
    const int n0   = blockIdx.y * 128;
    const int K    = DM_;

    f32x4 acc[4][4] = {};

    for (int kt = 0; kt < K; kt += 64) {
#pragma unroll
        for (int i = 0; i < 4; ++i) {
            int c   = i * 256 + t;
            int row = c >> 3;
            int kc  = c & 7;
            int cbase = i * 256 + wave * 64;
            const u16* gA = A  + (size_t)(m0 + row) * K + kt + kc * 8;
            const u16* gB = Bt + (size_t)(n0 + row) * K + kt + kc * 8;
            __builtin_amdgcn_global_load_lds((as1_cvp)gA, (as3_vp)(As + cbase * 8), 16, 0, 0);
            __builtin_amdgcn_global_load_lds((as1_cvp)gB, (as3_vp)(Bs + cbase * 8), 16, 0, 0);
        }
        __syncthreads();
#pragma unroll
        for (int ks = 0; ks < 2; ++ks) {
            bf16x8 af[4], bfr[4];
#pragma unroll
            for (int it = 0; it < 4; ++it)
                af[it] = *(const bf16x8*)(As + (wr * 64 + it * 16 + l16) * 64 + ks * 32 + quad * 8);
#pragma unroll
            for (int jt = 0; jt < 4; ++jt)
                bfr[jt] = *(const bf16x8*)(Bs + (wc * 64 + jt * 16 + l16) * 64 + ks * 32 + quad * 8);
#pragma unroll
            for (int it = 0; it < 4; ++it)
#pragma unroll
                for (int jt = 0; jt < 4; ++jt)
                    acc[it][jt] = __builtin_amdgcn_mfma_f32_16x16x32_bf16(
                        af[it], bfr[jt], acc[it][jt], 0, 0, 0);
        }
        __syncthreads();
    }

    if (z == 2) {
        // natural bf16 out (V)
#pragma unroll
        for (int it = 0; it < 4; ++it) {
            int row0 = m0 + wr * 64 + it * 16 + quad * 4;
#pragma unroll
            for (int jt = 0; jt < 4; ++jt) {
                int col = n0 + wc * 64 + jt * 16 + l16;
                float bv2 = bias[col];
#pragma unroll
                for (int r = 0; r < 4; ++r)
                    Vp[(size_t)(row0 + r) * DM_ + col] = f2b(acc[it][jt][r] + bv2);
            }
        }
    } else {
        // transposed per-head out (+ELU+1) via LDS: Ct[col][row], stride 136
        u16* OutT = z == 0 ? QpT : KpT;
        u16* Ct = smem;
#pragma unroll
        for (int it = 0; it < 4; ++it) {
            int row0 = wr * 64 + it * 16 + quad * 4;
#pragma unroll
            for (int jt = 0; jt < 4; ++jt) {
                int colr = wc * 64 + jt * 16 + l16;
                float bv2 = bias[n0 + colr];
                float x0 = acc[it][jt][0] + bv2;
                float x1 = acc[it][jt][1] + bv2;
                float x2 = acc[it][jt][2] + bv2;
                float x3 = acc[it][jt][3] + bv2;
                x0 = (x0 > 0.f) ? (x0 + 1.f) : __expf(x0);
                x1 = (x1 > 0.f) ? (x1 + 1.f) : __expf(x1);
                x2 = (x2 > 0.f) ? (x2 + 1.f) : __expf(x2);
                x3 = (x3 > 0.f) ? (x3 + 1.f) : __expf(x3);
                ushort4 o;
                o.x = f2b(x0); o.y = f2b(x1); o.z = f2b(x2); o.w = f2b(x3);
                *(ushort4*)&Ct[colr * 136 + row0] = o;
            }
        }
        __syncthreads();
        int b   = m0 >> 12;
        int seg = t & 15;
        int cg  = t >> 4;
#pragma unroll
        for (int iter = 0; iter < 8; ++iter) {
            int colIdx = iter * 16 + cg;
            int gcol = n0 + colIdx;
            int bh = b * 16 + (gcol >> 6);
            int e  = gcol & 63;
            uint4 v = *(const uint4*)&Ct[colIdx * 136 + seg * 8];
            *(uint4*)(OutT + ((size_t)bh << 18) + ((size_t)e << 12)
                      + (m0 & 4095) + seg * 8) = v;
        }
    }
}

// ---------------------------------------------------------------------------
// Final projection: C = ctx @ Wot^T + bo, fp32 natural out (m97 K-loop)
// ---------------------------------------------------------------------------
__global__ __launch_bounds__(256, 3) void gemm_out_kernel(
    const u16* __restrict__ A, const u16* __restrict__ Bt,
    const float* __restrict__ bias, float* __restrict__ Cout)
{
    __shared__ __align__(16) u16 smem[16384];
    u16* As = smem;
    u16* Bs = smem + 8192;

    const int t    = threadIdx.x;
    const int lane = t & 63;
    const int wave = t >> 6;
    const int wr   = wave >> 1;
    const int wc   = wave & 1;
    const int quad = lane >> 4;
    const int l16  = lane & 15;
    const int m0   = blockIdx.x * 128;
    const int n0   = blockIdx.y * 128;
    const int K    = DM_;

    f32x4 acc[4][4] = {};

    for (int kt = 0; kt < K; kt += 64) {
#pragma unroll
        for (int i = 0; i < 4; ++i) {
            int c   = i * 256 + t;
            int row = c >> 3;
            int kc  = c & 7;
            int cbase = i * 256 + wave * 64;
            const u16* gA = A  + (size_t)(m0 + row) * K + kt + kc * 8;
            const u16* gB = Bt + (size_t)(n0 + row) * K + kt + kc * 8;
            __builtin_amdgcn_global_load_lds((as1_cvp)gA, (as3_vp)(As + cbase * 8), 16, 0, 0);
            __builtin_amdgcn_global_load_lds((as1_cvp)gB, (as3_vp)(Bs + cbase * 8), 16, 0, 0);
        }
        __syncthreads();
#pragma unroll
        for (int ks = 0; ks < 2; ++ks) {
            bf16x8 af[4], bfr[4];
#pragma unroll
            for (int it = 0; it < 4; ++it)
                af[it] = *(const bf16x8*)(As + (wr * 64 + it * 16 + l16) * 64 + ks * 32 + quad * 8);
#pragma unroll
            for (int jt = 0; jt < 4; ++jt)
                bfr[jt] = *(const bf16x8*)(Bs + (wc * 64 + jt * 16 + l16) * 64 + ks * 32 + quad * 8);
#pragma unroll
            for (int it = 0; it < 4; ++it)
#pragma unroll
                for (int jt = 0; jt < 4; ++jt)
                    acc[it][jt] = __builtin_amdgcn_mfma_f32_16x16x32_bf16(
                        af[it], bfr[jt], acc[it][jt], 0, 0, 0);
        }
        __syncthreads();
    }

#pragma unroll
    for (int it = 0; it < 4; ++it) {
        int row0 = m0 + wr * 64 + it * 16 + quad * 4;
#pragma unroll
        for (int jt = 0; jt < 4; ++jt) {
            int col = n0 + wc * 64 + jt * 16 + l16;
            float bv = bias[col];
#pragma unroll
            for (int r = 0; r < 4; ++r)
                Cout[(size_t)(row0 + r) * DM_ + col] = acc[it][jt][r] + bv;
        }
    }
}

// ---------------------------------------------------------------------------
// attn_s: S[bh][e][d] += sum_l KpT[bh][e][l] * QpT[bh][d][l]   (MFMA, k=l)
// 512 l per block (halved atomic count vs 256).
// + denom[bh][l] = sum_e QpT[e][l]*KpT[e][l] + 1e-6
// ---------------------------------------------------------------------------
__global__ __launch_bounds__(256) void attn_s_kernel(
    const u16* __restrict__ QpT, const u16* __restrict__ KpT,
    float* __restrict__ S, float* __restrict__ denom)
{
    const int t    = threadIdx.x;
    const int lane = t & 63;
    const int wave = t >> 6;
    const int quad = lane >> 4;
    const int l16  = lane & 15;
    const int bh   = blockIdx.x;
    const int lc   = blockIdx.y * 512;

    const u16* baseQ = QpT + ((size_t)bh << 18);
    const u16* baseK = KpT + ((size_t)bh << 18);

    f32x4 acc[4] = {};
    const u16* arow = baseK + (size_t)(wave * 16 + l16) * 4096 + lc;
#pragma unroll 4
    for (int ks = 0; ks < 16; ++ks) {
        int koff = ks * 32 + quad * 8;
        bf16x8 a = *(const bf16x8*)(arow + koff);
#pragma unroll
        for (int dt = 0; dt < 4; ++dt) {
            bf16x8 b = *(const bf16x8*)(baseQ + (size_t)(dt * 16 + l16) * 4096 + lc + koff);
            acc[dt] = __builtin_amdgcn_mfma_f32_16x16x32_bf16(a, b, acc[dt], 0, 0, 0);
        }
    }
    float* Sb = S + (size_t)bh * 4096;
#pragma unroll
    for (int dt = 0; dt < 4; ++dt)
#pragma unroll
        for (int r = 0; r < 4; ++r)
            atomicAdd(&Sb[(wave * 16 + quad * 4 + r) * 64 + dt * 16 + l16], acc[dt][r]);

    // denom: all 256 threads, 2 consecutive l each -> covers 512 l
    {
        float s0 = 0.f, s1 = 0.f;
        int off = lc + 2 * t;
#pragma unroll 8
        for (int e = 0; e < 64; ++e) {
            unsigned int qv = *(const unsigned int*)(baseQ + (size_t)e * 4096 + off);
            unsigned int kv = *(const unsigned int*)(baseK + (size_t)e * 4096 + off);
            s0 += b2f((u16)(qv & 0xffff)) * b2f((u16)(kv & 0xffff));
            s1 += b2f((u16)(qv >> 16))   * b2f((u16)(kv >> 16));
        }
        denom[(size_t)bh * 4096 + off]     = s0 + 1e-6f;
        denom[(size_t)bh * 4096 + off + 1] = s1 + 1e-6f;
    }
}

// ---------------------------------------------------------------------------
// attn_out: ctx[b][l][h*64+d] = (sum_e V[l][e] * S[e][d]) / denom[l]  (MFMA)
// ---------------------------------------------------------------------------
__global__ __launch_bounds__(256) void attn_out_kernel(
    const u16* __restrict__ Vp, const float* __restrict__ S,
    const float* __restrict__ denom, u16* __restrict__ ctx)
{
    __shared__ __align__(16) u16 Sb[64 * 64];   // Sb[d][e], e contiguous
    __shared__ float dsh[256];
    const int t    = threadIdx.x;
    const int lane = t & 63;
    const int wave = t >> 6;
    const int quad = lane >> 4;
    const int l16  = lane & 15;
    const int bh   = blockIdx.x;
    const int b    = bh >> 4, h = bh & 15;
    const int lc   = blockIdx.y * 256;

    {
        const float* Sg = S + (size_t)bh * 4096;
        int e = t >> 2, d0 = (t & 3) * 16;
#pragma unroll
        for (int i = 0; i < 16; ++i)
            Sb[(d0 + i) * 64 + e] = f2b(Sg[e * 64 + d0 + i]);
        dsh[t] = denom[(size_t)bh * 4096 + lc + t];
    }
    __syncthreads();

    const u16* Abase = Vp + (size_t)b * L_ * DM_ + (size_t)(lc + wave * 64 + l16) * DM_ + h * 64;
    f32x4 acc[4][4] = {};
#pragma unroll
    for (int ks = 0; ks < 2; ++ks) {
        int koff = ks * 32 + quad * 8;
        bf16x8 af[4], bfr[4];
#pragma unroll
        for (int lt = 0; lt < 4; ++lt)
            af[lt] = *(const bf16x8*)(Abase + (size_t)(lt * 16) * DM_ + koff);
#pragma unroll
        for (int dt = 0; dt < 4; ++dt)
            bfr[dt] = *(const bf16x8*)(Sb + (dt * 16 + l16) * 64 + koff);
#pragma unroll
        for (int lt = 0; lt < 4; ++lt)
#pragma unroll
            for (int dt = 0; dt < 4; ++dt)
                acc[lt][dt] = __builtin_amdgcn_mfma_f32_16x16x32_bf16(
                    af[lt], bfr[dt], acc[lt][dt], 0, 0, 0);
    }

    u16* cbase = ctx + (size_t)b * L_ * DM_ + h * 64;
#pragma unroll
    for (int lt = 0; lt < 4; ++lt) {
        int lrow0 = wave * 64 + lt * 16 + quad * 4;
        float inv[4];
#pragma unroll
        for (int r = 0; r < 4; ++r) inv[r] = 1.f / dsh[lrow0 + r];
#pragma unroll
        for (int dt = 0; dt < 4; ++dt) {
            int d = dt * 16 + l16;
#pragma unroll
            for (int r = 0; r < 4; ++r)
                cbase[(size_t)(lc + lrow0 + r) * DM_ + d] = f2b(acc[lt][dt][r] * inv[r]);
        }
    }
}

// ---------------------------------------------------------------------------
extern "C" void kernel_launch(void* const* d_in, const int* in_sizes, int n_in,
                              void* d_out, int out_size, void* d_ws, size_t ws_size,
                              hipStream_t stream)
{
    const float* query = (const float*)d_in[0];
    const float* key   = (const float*)d_in[1];
    const float* value = (const float*)d_in[2];
    const float* Wq = (const float*)d_in[3];  const float* bq = (const float*)d_in[4];
    const float* Wk = (const float*)d_in[5];  const float* bk = (const float*)d_in[6];
    const float* Wv = (const float*)d_in[7];  const float* bv = (const float*)d_in[8];
    const float* Wo = (const float*)d_in[9];  const float* bo = (const float*)d_in[10];

    const size_t SZ = (size_t)M_ * DM_ * sizeof(u16);   // 16.78 MB per bf16 tensor
    char* ws = (char*)d_ws;
    u16* qb  = (u16*)(ws + 0 * SZ);
    u16* kb  = (u16*)(ws + 1 * SZ);
    u16* vb  = (u16*)(ws + 2 * SZ);
    u16* QpT = (u16*)(ws + 3 * SZ);   // [bh][e][l] l-contiguous
    u16* KpT = (u16*)(ws + 4 * SZ);
    u16* Vp  = qb;    // qb dead after Q projection? NO - batched launch: use own buffer
    u16* ctx = kb;    // kb dead after K projection? NO - batched launch: use own buffer
    // NOTE: with the batched QKV launch, qb/kb/vb are all live simultaneously as
    // inputs while Vp is written. Vp must NOT alias qb. Give V and ctx fresh slots.
    u16* Wqt = (u16*)(ws + 5 * SZ);
    u16* Wkt = Wqt + (size_t)DM_ * DM_;
    u16* Wvt = Wkt + (size_t)DM_ * DM_;
    u16* Wot = Wvt + (size_t)DM_ * DM_;
    float* S     = (float*)(ws + 5 * SZ + 4 * (size_t)DM_ * DM_ * sizeof(u16));
    float* denom = S + (size_t)B_ * H_ * D_ * D_;
    u16* Vp2  = (u16*)((char*)(denom + (size_t)B_ * H_ * L_) + 256);
    u16* ctx2 = (u16*)((char*)Vp2 + SZ);
    Vp = Vp2; ctx = ctx2;

    // 1. weights: transpose + cast to bf16 (N x K), one launch
    transpose4_cast_kernel<<<dim3(32, 32, 4), dim3(32, 8), 0, stream>>>(
        Wq, Wk, Wv, Wo, Wqt, Wkt, Wvt, Wot);

    // 2. activations: cast to bf16, one launch
    int n4 = M_ * DM_ / 4;
    cast3_bf16_kernel<<<dim3(n4 / 256, 1, 3), 256, 0, stream>>>(
        query, key, value, qb, kb, vb, n4);

    // 3. zero S accumulator
    int nS = B_ * H_ * D_ * D_;
    zero_f32_kernel<<<nS / 256, 256, 0, stream>>>(S, nS);

    // 4. QKV projections, one launch (1536 blocks -> 3 blocks/CU resident)
    gemm_qkv_kernel<<<dim3(M_ / 128, DM_ / 128, 3), 256, 0, stream>>>(
        qb, kb, vb, Wqt, Wkt, Wvt, bq, bk, bv, QpT, KpT, Vp);

    // 5. S = K^T Q per head (+denom), MFMA over l, 512 l/block
    attn_s_kernel<<<dim3(B_ * H_, L_ / 512), 256, 0, stream>>>(QpT, KpT, S, denom);

    // 6. out = V S / denom -> ctx (bf16, combined-head layout), MFMA
    attn_out_kernel<<<dim3(B_ * H_, L_ / 256), 256, 0, stream>>>(Vp, S, denom, ctx);

    // 7. final projection -> fp32 d_out
    gemm_out_kernel<<<dim3(M_ / 128, DM_ / 128), 256, 0, stream>>>(
        ctx, Wot, bo, (float*)d_out);
}